// Round 8
// baseline (247.695 us; speedup 1.0000x reference)
//
#include <hip/hip_runtime.h>
#include <hip/hip_bf16.h>

#define B_   2
#define S_   1024
#define E_   2048
#define NH_  16
#define DH_  128
#define EPS_ 1e-6f

using half8   = __attribute__((ext_vector_type(8))) _Float16;
using floatx4 = __attribute__((ext_vector_type(4))) float;

__device__ __forceinline__ half8 cvt8h(const float* __restrict__ p) {
    float4 a = *(const float4*)p;
    float4 b = *(const float4*)(p + 4);
    half8 r;
    r[0] = (_Float16)a.x; r[1] = (_Float16)a.y;
    r[2] = (_Float16)a.z; r[3] = (_Float16)a.w;
    r[4] = (_Float16)b.x; r[5] = (_Float16)b.y;
    r[6] = (_Float16)b.z; r[7] = (_Float16)b.w;
    return r;
}
__device__ __forceinline__ half8 cvt2f4(float4 a, float4 b) {
    half8 r;
    r[0] = (_Float16)a.x; r[1] = (_Float16)a.y;
    r[2] = (_Float16)a.z; r[3] = (_Float16)a.w;
    r[4] = (_Float16)b.x; r[5] = (_Float16)b.y;
    r[6] = (_Float16)b.z; r[7] = (_Float16)b.w;
    return r;
}

// ---------------------------------------------------------------------------
// Kernel 1: gate GEMM, K-split x8, no atomics (disjoint partial buffers).
// ---------------------------------------------------------------------------
__global__ __launch_bounds__(256, 4) void gates_kernel(
    const float* __restrict__ q, const float* __restrict__ k,
    const float* __restrict__ v, const float* __restrict__ Wi,
    const float* __restrict__ Wf, float* __restrict__ pre_i,
    float* __restrict__ pre_f)
{
    __shared__ __attribute__((aligned(16))) _Float16 xs[32 * 264];
    __shared__ __attribute__((aligned(16))) _Float16 wt[32 * 264];

    const int t    = threadIdx.x;
    const int w    = t >> 6, lane = t & 63, quad = lane >> 4, l15 = lane & 15;
    const int mw   = w & 1, nw = w >> 1;
    const int m0   = blockIdx.x * 32;
    const int by   = blockIdx.y;
    const int kbase = by * 768;

    floatx4 acc = {0.f, 0.f, 0.f, 0.f};

    for (int c = 0; c < 3; ++c) {
        __syncthreads();
        const int e0   = kbase + c * 256;
        const int tsel = e0 >> 11;            // 0:q 1:k 2:v
        const int el0  = e0 & 2047;
        const float* xb = (tsel == 0) ? q : (tsel == 1) ? k : v;
        #pragma unroll
        for (int i = 0; i < 4; ++i) {
            int g = t + i * 256;
            int row = g >> 5, grp = g & 31;
            half8 s8 = cvt8h(xb + (size_t)(m0 + row) * E_ + el0 + grp * 8);
            *(half8*)(&xs[row * 264 + grp * 8]) = s8;
        }
        {
            const int kk = t;
            const float* wiRow = Wi + (size_t)(e0 + kk) * NH_;
            const float* wfRow = Wf + (size_t)(e0 + kk) * NH_;
            float wif[16], wff[16];
            #pragma unroll
            for (int i4 = 0; i4 < 4; ++i4) {
                float4 a = *(const float4*)(wiRow + i4 * 4);
                wif[i4*4+0]=a.x; wif[i4*4+1]=a.y; wif[i4*4+2]=a.z; wif[i4*4+3]=a.w;
                float4 b = *(const float4*)(wfRow + i4 * 4);
                wff[i4*4+0]=b.x; wff[i4*4+1]=b.y; wff[i4*4+2]=b.z; wff[i4*4+3]=b.w;
            }
            #pragma unroll
            for (int hh = 0; hh < 16; ++hh) wt[hh * 264 + kk]        = (_Float16)wif[hh];
            #pragma unroll
            for (int hh = 0; hh < 16; ++hh) wt[(16 + hh) * 264 + kk] = (_Float16)wff[hh];
        }
        __syncthreads();
        #pragma unroll
        for (int ks = 0; ks < 8; ++ks) {
            half8 af = *(const half8*)(&xs[(mw * 16 + l15) * 264 + ks * 32 + quad * 8]);
            half8 bw = *(const half8*)(&wt[(nw * 16 + l15) * 264 + ks * 32 + quad * 8]);
            acc = __builtin_amdgcn_mfma_f32_16x16x32_f16(af, bw, acc, 0, 0, 0);
        }
    }
    #pragma unroll
    for (int reg = 0; reg < 4; ++reg) {
        int m   = m0 + mw * 16 + quad * 4 + reg;
        int b   = m >> 10, s = m & 1023;
        int col = nw * 16 + l15;
        float vacc = acc[reg];
        if (col < 16)
            pre_i[((size_t)(by * 32 + b * NH_ + col)) * S_ + s] = vacc;
        else
            pre_f[((size_t)(by * 32 + b * NH_ + col - 16)) * S_ + s] = vacc;
    }
}

// ---------------------------------------------------------------------------
// Kernel 2: sum 8 partials + bias + log_sigmoid + scans.
// ---------------------------------------------------------------------------
__global__ void scan_kernel(const float* __restrict__ pre_i,
                            const float* __restrict__ pre_f,
                            float* __restrict__ Aj, float* __restrict__ Cq,
                            float* __restrict__ NFo, const float* __restrict__ bi,
                            const float* __restrict__ bfb)
{
    const int bh   = blockIdx.x;
    const int h    = bh & 15;
    const int lane = threadIdx.x;
    const float bih = bi[h], bfh = bfb[h];
    float carryF = 0.f, carryM = -3.0e38f;
    for (int it = 0; it < 16; ++it) {
        int idx = it * 64 + lane;
        float igv = bih, x = bfh;
        #pragma unroll
        for (int y = 0; y < 8; ++y) {
            igv += pre_i[((size_t)(y * 32 + bh)) * S_ + idx];
            x   += pre_f[((size_t)(y * 32 + bh)) * S_ + idx];
        }
        float lfv = (x >= 0.f) ? -log1pf(__expf(-x)) : (x - log1pf(__expf(x)));
        float sc = lfv;
        #pragma unroll
        for (int off = 1; off < 64; off <<= 1) {
            float o = __shfl_up(sc, off);
            if (lane >= off) sc += o;
        }
        float F = carryF + sc;
        float a = igv - F;
        float ms = a;
        #pragma unroll
        for (int off = 1; off < 64; off <<= 1) {
            float o = __shfl_up(ms, off);
            if (lane >= off) ms = fmaxf(ms, o);
        }
        float M = fmaxf(carryM, ms);
        size_t o = (size_t)bh * S_ + idx;
        Aj[o]  = a;
        Cq[o]  = -M;
        NFo[o] = expf(fminf(-(F + M), 80.f));
        carryF = __shfl(F, 63);
        carryM = __shfl(M, 63);
    }
}

// ---------------------------------------------------------------------------
// Kernel 3: fused causal attention. Single compute run [QK,P,PV] per iter
// (Pb is wave-private -> no barrier between P and PV), then b1 / stage / b2.
// All LDS single-buffered: 44.2 KB -> 3 blocks/CU.
// ---------------------------------------------------------------------------
__global__ __launch_bounds__(256, 3) void attn_kernel(
    const float* __restrict__ q, const float* __restrict__ k,
    const float* __restrict__ v, const float* __restrict__ Aj,
    const float* __restrict__ Cq, const float* __restrict__ NFi,
    const float* __restrict__ lnsc, float* __restrict__ out)
{
    __shared__ __attribute__((aligned(16))) _Float16 Ks[64 * 136];
    __shared__ __attribute__((aligned(16))) _Float16 Vt[128 * 72];
    __shared__ __attribute__((aligned(16))) _Float16 Pb[64 * 72];
    __shared__ float aj[64];

    const int t    = threadIdx.x;
    const int w    = t >> 6, lane = t & 63, quad = lane >> 4, l15 = lane & 15;
    const int L    = blockIdx.x;
    int qi, bh;
    if (L < 256) { qi = L >> 5;                bh = L & 31; }
    else         { qi = 15 - ((L - 256) >> 5); bh = (L - 256) & 31; }
    const int b    = bh >> 4, h = bh & 15;
    const size_t rowbase = (size_t)b * S_;
    const int q0   = qi * 64;
    const int srow = t >> 4, sgrp = t & 15;

    // per-lane row constants (no LDS)
    float ci_r[4], nfv_r[4];
    #pragma unroll
    for (int reg = 0; reg < 4; ++reg) {
        int rl = w * 16 + quad * 4 + reg;
        ci_r[reg]  = Cq[(size_t)bh * S_ + q0 + rl];
        nfv_r[reg] = NFi[(size_t)bh * S_ + q0 + rl];
    }
    // Q A-frags straight from global: A[m=w*16+l15][k=ks*32+quad*8+j]
    half8 aq[4];
    {
        const float* qrow = q + (rowbase + q0 + w * 16 + l15) * E_ + h * DH_;
        #pragma unroll
        for (int ks = 0; ks < 4; ++ks)
            aq[ks] = cvt8h(qrow + ks * 32 + quad * 8);
    }

    // ---- raw prefetch tile 0 ----
    float4 kraw[4][2], vraw[4][2];
    float ajreg = 0.f;
    #pragma unroll
    for (int i = 0; i < 4; ++i) {
        const float* gp = k + (rowbase + (srow + i * 16)) * E_ + h * DH_ + sgrp * 8;
        kraw[i][0] = *(const float4*)gp;  kraw[i][1] = *(const float4*)(gp + 4);
        const float* vp = v + (rowbase + (srow + i * 16)) * E_ + h * DH_ + sgrp * 8;
        vraw[i][0] = *(const float4*)vp;  vraw[i][1] = *(const float4*)(vp + 4);
    }
    if (t < 64) ajreg = Aj[(size_t)bh * S_ + t];

    // ---- cvt + stage tile 0 ----
    #pragma unroll
    for (int i = 0; i < 4; ++i) {
        int row = srow + i * 16;
        *(half8*)(&Ks[row * 136 + sgrp * 8]) = cvt2f4(kraw[i][0], kraw[i][1]);
        half8 vh = cvt2f4(vraw[i][0], vraw[i][1]);
        #pragma unroll
        for (int uu = 0; uu < 8; ++uu) {        // lane-rotated scatter
            int u = (uu + lane) & 7;
            Vt[(sgrp * 8 + u) * 72 + row] = vh[u];
        }
    }
    if (t < 64) aj[t] = ajreg;
    __syncthreads();

    floatx4 acc_h[8];
    #pragma unroll
    for (int i = 0; i < 8; ++i) acc_h[i] = (floatx4){0.f, 0.f, 0.f, 0.f};
    float lrun[4] = {0.f, 0.f, 0.f, 0.f};
    const float rscale = 0.08838834764831845f;   // 1/sqrt(128)

    for (int kt = 0; kt <= qi; ++kt) {
        // issue next-tile RAW loads (vmcnt waits land in the staging section)
        if (kt < qi) {
            const int j0n = (kt + 1) * 64;
            #pragma unroll
            for (int i = 0; i < 4; ++i) {
                const float* gp = k + (rowbase + j0n + (srow + i * 16)) * E_ + h * DH_ + sgrp * 8;
                kraw[i][0] = *(const float4*)gp;  kraw[i][1] = *(const float4*)(gp + 4);
                const float* vp = v + (rowbase + j0n + (srow + i * 16)) * E_ + h * DH_ + sgrp * 8;
                vraw[i][0] = *(const float4*)vp;  vraw[i][1] = *(const float4*)(vp + 4);
            }
            if (t < 64) ajreg = Aj[(size_t)bh * S_ + j0n + t];
        }

        // ---- compute run: QK -> P -> PV, no internal barrier ----
        floatx4 sacc[4];
        #pragma unroll
        for (int nt = 0; nt < 4; ++nt) sacc[nt] = (floatx4){0.f, 0.f, 0.f, 0.f};
        #pragma unroll
        for (int ks = 0; ks < 4; ++ks) {
            #pragma unroll
            for (int nt = 0; nt < 4; ++nt) {
                half8 bk = *(const half8*)(&Ks[(nt * 16 + l15) * 136 + ks * 32 + quad * 8]);
                sacc[nt] = __builtin_amdgcn_mfma_f32_16x16x32_f16(aq[ks], bk, sacc[nt], 0, 0, 0);
            }
        }
        const bool diag = (kt == qi);
        #pragma unroll
        for (int nt = 0; nt < 4; ++nt) {
            int jl = nt * 16 + l15;
            float a_j = aj[jl];
            #pragma unroll
            for (int reg = 0; reg < 4; ++reg) {
                int rl = w * 16 + quad * 4 + reg;
                float p = 0.f;
                if (!diag || (jl <= rl))
                    p = sacc[nt][reg] * rscale * __expf(fminf(ci_r[reg] + a_j, 0.f));
                lrun[reg] += p;
                Pb[rl * 72 + jl] = (_Float16)p;    // wave-private rows
            }
        }
        // PV: A-frags from own Pb rows (same-wave DS in-order), B from Vt
        #pragma unroll
        for (int ks2 = 0; ks2 < 2; ++ks2) {
            half8 ap = *(const half8*)(&Pb[(w * 16 + l15) * 72 + ks2 * 32 + quad * 8]);
            #pragma unroll
            for (int nt2 = 0; nt2 < 8; ++nt2) {
                half8 bv = *(const half8*)(&Vt[(nt2 * 16 + l15) * 72 + ks2 * 32 + quad * 8]);
                acc_h[nt2] = __builtin_amdgcn_mfma_f32_16x16x32_f16(ap, bv, acc_h[nt2], 0, 0, 0);
            }
        }

        __syncthreads();   // b1: all reads of Ks/Vt/aj for tile kt complete
        if (kt < qi) {
            #pragma unroll
            for (int i = 0; i < 4; ++i) {
                int row = srow + i * 16;
                *(half8*)(&Ks[row * 136 + sgrp * 8]) = cvt2f4(kraw[i][0], kraw[i][1]);
                half8 vh = cvt2f4(vraw[i][0], vraw[i][1]);
                #pragma unroll
                for (int uu = 0; uu < 8; ++uu) {
                    int u = (uu + lane) & 7;
                    Vt[(sgrp * 8 + u) * 72 + row] = vh[u];
                }
            }
            if (t < 64) aj[t] = ajreg;
            __syncthreads();   // b2: staging of tile kt+1 visible
        }
    }

    // epilogue: normalizer + per-head LayerNorm over DH
    #pragma unroll
    for (int reg = 0; reg < 4; ++reg) {
        float l = lrun[reg];
        #pragma unroll
        for (int off = 1; off < 16; off <<= 1) l += __shfl_xor(l, off);
        int rl = w * 16 + quad * 4 + reg;
        float nrm = fmaxf(fabsf(l), nfv_r[reg]) + EPS_;
        float inv = 1.f / nrm;
        float hv[8];
        float sum = 0.f, sq = 0.f;
        #pragma unroll
        for (int nt2 = 0; nt2 < 8; ++nt2) {
            float x = acc_h[nt2][reg] * inv;
            hv[nt2] = x; sum += x; sq += x * x;
        }
        #pragma unroll
        for (int off = 1; off < 16; off <<= 1) {
            sum += __shfl_xor(sum, off);
            sq  += __shfl_xor(sq, off);
        }
        float mean = sum * (1.f / 128.f);
        float var  = fmaxf(sq * (1.f / 128.f) - mean * mean, 0.f);
        float rstd = rsqrtf(var + EPS_);
        size_t orow = (rowbase + q0 + rl) * E_ + h * DH_;
        #pragma unroll
        for (int nt2 = 0; nt2 < 8; ++nt2) {
            int d = nt2 * 16 + l15;
            out[orow + d] = (hv[nt2] - mean) * rstd * lnsc[h * DH_ + d];
        }
    }
}

// ---------------------------------------------------------------------------
extern "C" void kernel_launch(void* const* d_in, const int* in_sizes, int n_in,
                              void* d_out, int out_size, void* d_ws, size_t ws_size,
                              hipStream_t stream)
{
    const float* q    = (const float*)d_in[0];
    const float* k    = (const float*)d_in[1];
    const float* v    = (const float*)d_in[2];
    const float* Wi   = (const float*)d_in[3];
    const float* bi   = (const float*)d_in[4];
    const float* Wf   = (const float*)d_in[5];
    const float* bfb  = (const float*)d_in[6];
    const float* lnsc = (const float*)d_in[7];
    float* out        = (float*)d_out;

    const int NS  = B_ * NH_ * S_;       // 32768
    float* pre_i = (float*)d_ws;         // [8][32][1024] partials
    float* pre_f = pre_i + 8 * NS;
    float* Aj    = pre_f + 8 * NS;
    float* Cq    = Aj + NS;
    float* NFa   = Cq + NS;              // total ~2.4 MB

    gates_kernel<<<dim3(64, 8), 256, 0, stream>>>(q, k, v, Wi, Wf, pre_i, pre_f);
    scan_kernel<<<dim3(32), 64, 0, stream>>>(pre_i, pre_f, Aj, Cq, NFa, bi, bfb);
    attn_kernel<<<dim3(512), 256, 0, stream>>>(q, k, v, Aj, Cq, NFa, lnsc, out);
}

// Round 9
// 203.714 us; speedup vs baseline: 1.2159x; 1.2159x over previous
//
#include <hip/hip_runtime.h>
#include <hip/hip_bf16.h>

#define B_   2
#define S_   1024
#define E_   2048
#define NH_  16
#define DH_  128
#define EPS_ 1e-6f

using half8   = __attribute__((ext_vector_type(8))) _Float16;
using floatx4 = __attribute__((ext_vector_type(4))) float;

__device__ __forceinline__ half8 cvt8h(const float* __restrict__ p) {
    float4 a = *(const float4*)p;
    float4 b = *(const float4*)(p + 4);
    half8 r;
    r[0] = (_Float16)a.x; r[1] = (_Float16)a.y;
    r[2] = (_Float16)a.z; r[3] = (_Float16)a.w;
    r[4] = (_Float16)b.x; r[5] = (_Float16)b.y;
    r[6] = (_Float16)b.z; r[7] = (_Float16)b.w;
    return r;
}

// ---------------------------------------------------------------------------
// Kernel 0: pre-convert q,k -> f16 [bh][s][d]; v -> f16 TRANSPOSED [bh][d][s].
// Reads everything once (48 MB), writes 24 MB. LDS transpose for V.
// ---------------------------------------------------------------------------
__global__ __launch_bounds__(256, 2) void prep_kernel(
    const float* __restrict__ q, const float* __restrict__ k,
    const float* __restrict__ v, _Float16* __restrict__ qh,
    _Float16* __restrict__ kh, _Float16* __restrict__ vtg)
{
    __shared__ __attribute__((aligned(16))) _Float16 vs[64 * 136];
    const int t  = threadIdx.x;
    const int st = blockIdx.x, bh = blockIdx.y;
    const int b  = bh >> 4, h = bh & 15;
    const int s0 = st * 64;
    const int r  = t >> 2, d0 = (t & 3) * 32;
    const size_t gin  = ((size_t)b * S_ + s0 + r) * E_ + h * DH_ + d0;
    const size_t gout = ((size_t)bh * S_ + s0 + r) * DH_ + d0;
    #pragma unroll
    for (int i = 0; i < 4; ++i)
        *(half8*)(qh + gout + i * 8) = cvt8h(q + gin + i * 8);
    #pragma unroll
    for (int i = 0; i < 4; ++i)
        *(half8*)(kh + gout + i * 8) = cvt8h(k + gin + i * 8);
    #pragma unroll
    for (int i = 0; i < 4; ++i)
        *(half8*)(&vs[r * 136 + d0 + i * 8]) = cvt8h(v + gin + i * 8);
    __syncthreads();
    const int d = t >> 1, j0 = (t & 1) * 32;
    _Float16 tmp[32];
    #pragma unroll
    for (int jj = 0; jj < 32; ++jj)
        tmp[jj] = vs[(j0 + jj) * 136 + d];      // 2-way banks (free)
    const size_t vout = ((size_t)bh * DH_ + d) * S_ + s0 + j0;
    #pragma unroll
    for (int i = 0; i < 4; ++i)
        *(half8*)(vtg + vout + i * 8) = *(half8*)(&tmp[i * 8]);
}

// ---------------------------------------------------------------------------
// Kernel 1: gate GEMM, K-split x8, no atomics (disjoint partial buffers).
// ---------------------------------------------------------------------------
__global__ __launch_bounds__(256, 4) void gates_kernel(
    const float* __restrict__ q, const float* __restrict__ k,
    const float* __restrict__ v, const float* __restrict__ Wi,
    const float* __restrict__ Wf, float* __restrict__ pre_i,
    float* __restrict__ pre_f)
{
    __shared__ __attribute__((aligned(16))) _Float16 xs[32 * 264];
    __shared__ __attribute__((aligned(16))) _Float16 wt[32 * 264];

    const int t    = threadIdx.x;
    const int w    = t >> 6, lane = t & 63, quad = lane >> 4, l15 = lane & 15;
    const int mw   = w & 1, nw = w >> 1;
    const int m0   = blockIdx.x * 32;
    const int by   = blockIdx.y;
    const int kbase = by * 768;

    floatx4 acc = {0.f, 0.f, 0.f, 0.f};

    for (int c = 0; c < 3; ++c) {
        __syncthreads();
        const int e0   = kbase + c * 256;
        const int tsel = e0 >> 11;            // 0:q 1:k 2:v
        const int el0  = e0 & 2047;
        const float* xb = (tsel == 0) ? q : (tsel == 1) ? k : v;
        #pragma unroll
        for (int i = 0; i < 4; ++i) {
            int g = t + i * 256;
            int row = g >> 5, grp = g & 31;
            half8 s8 = cvt8h(xb + (size_t)(m0 + row) * E_ + el0 + grp * 8);
            *(half8*)(&xs[row * 264 + grp * 8]) = s8;
        }
        {
            const int kk = t;
            const float* wiRow = Wi + (size_t)(e0 + kk) * NH_;
            const float* wfRow = Wf + (size_t)(e0 + kk) * NH_;
            float wif[16], wff[16];
            #pragma unroll
            for (int i4 = 0; i4 < 4; ++i4) {
                float4 a = *(const float4*)(wiRow + i4 * 4);
                wif[i4*4+0]=a.x; wif[i4*4+1]=a.y; wif[i4*4+2]=a.z; wif[i4*4+3]=a.w;
                float4 b = *(const float4*)(wfRow + i4 * 4);
                wff[i4*4+0]=b.x; wff[i4*4+1]=b.y; wff[i4*4+2]=b.z; wff[i4*4+3]=b.w;
            }
            #pragma unroll
            for (int hh = 0; hh < 16; ++hh) wt[hh * 264 + kk]        = (_Float16)wif[hh];
            #pragma unroll
            for (int hh = 0; hh < 16; ++hh) wt[(16 + hh) * 264 + kk] = (_Float16)wff[hh];
        }
        __syncthreads();
        #pragma unroll
        for (int ks = 0; ks < 8; ++ks) {
            half8 af = *(const half8*)(&xs[(mw * 16 + l15) * 264 + ks * 32 + quad * 8]);
            half8 bw = *(const half8*)(&wt[(nw * 16 + l15) * 264 + ks * 32 + quad * 8]);
            acc = __builtin_amdgcn_mfma_f32_16x16x32_f16(af, bw, acc, 0, 0, 0);
        }
    }
    #pragma unroll
    for (int reg = 0; reg < 4; ++reg) {
        int m   = m0 + mw * 16 + quad * 4 + reg;
        int b   = m >> 10, s = m & 1023;
        int col = nw * 16 + l15;
        float vacc = acc[reg];
        if (col < 16)
            pre_i[((size_t)(by * 32 + b * NH_ + col)) * S_ + s] = vacc;
        else
            pre_f[((size_t)(by * 32 + b * NH_ + col - 16)) * S_ + s] = vacc;
    }
}

// ---------------------------------------------------------------------------
// Kernel 2: sum 8 partials + bias + log_sigmoid + scans.
// ---------------------------------------------------------------------------
__global__ void scan_kernel(const float* __restrict__ pre_i,
                            const float* __restrict__ pre_f,
                            float* __restrict__ Aj, float* __restrict__ Cq,
                            float* __restrict__ NFo, const float* __restrict__ bi,
                            const float* __restrict__ bfb)
{
    const int bh   = blockIdx.x;
    const int h    = bh & 15;
    const int lane = threadIdx.x;
    const float bih = bi[h], bfh = bfb[h];
    float carryF = 0.f, carryM = -3.0e38f;
    for (int it = 0; it < 16; ++it) {
        int idx = it * 64 + lane;
        float igv = bih, x = bfh;
        #pragma unroll
        for (int y = 0; y < 8; ++y) {
            igv += pre_i[((size_t)(y * 32 + bh)) * S_ + idx];
            x   += pre_f[((size_t)(y * 32 + bh)) * S_ + idx];
        }
        float lfv = (x >= 0.f) ? -log1pf(__expf(-x)) : (x - log1pf(__expf(x)));
        float sc = lfv;
        #pragma unroll
        for (int off = 1; off < 64; off <<= 1) {
            float o = __shfl_up(sc, off);
            if (lane >= off) sc += o;
        }
        float F = carryF + sc;
        float a = igv - F;
        float ms = a;
        #pragma unroll
        for (int off = 1; off < 64; off <<= 1) {
            float o = __shfl_up(ms, off);
            if (lane >= off) ms = fmaxf(ms, o);
        }
        float M = fmaxf(carryM, ms);
        size_t o = (size_t)bh * S_ + idx;
        Aj[o]  = a;
        Cq[o]  = -M;
        NFo[o] = expf(fminf(-(F + M), 80.f));
        carryF = __shfl(F, 63);
        carryM = __shfl(M, 63);
    }
}

// ---------------------------------------------------------------------------
// Kernel 3: fused causal attention on pre-converted f16 inputs.
// Merged compute run [QK,P,PV] (Pb wave-private), f16 register prefetch
// (32 VGPRs, no spill), single-buffered LDS 45.3 KB -> 3 blocks/CU.
// ---------------------------------------------------------------------------
__global__ __launch_bounds__(256, 2) void attn_kernel(
    const _Float16* __restrict__ qh, const _Float16* __restrict__ kh,
    const _Float16* __restrict__ vtg, const float* __restrict__ Aj,
    const float* __restrict__ Cq, const float* __restrict__ NFi,
    const float* __restrict__ lnsc, float* __restrict__ out)
{
    __shared__ __attribute__((aligned(16))) _Float16 Ks[64 * 136];
    __shared__ __attribute__((aligned(16))) _Float16 Vt[128 * 72];
    __shared__ __attribute__((aligned(16))) _Float16 Pb[64 * 72];
    __shared__ float aj[64];

    const int t    = threadIdx.x;
    const int w    = t >> 6, lane = t & 63, quad = lane >> 4, l15 = lane & 15;
    const int L    = blockIdx.x;
    int qi, bh;
    if (L < 256) { qi = L >> 5;                bh = L & 31; }
    else         { qi = 15 - ((L - 256) >> 5); bh = (L - 256) & 31; }
    const int b    = bh >> 4, h = bh & 15;
    const int q0   = qi * 64;
    const int krow = t >> 2, kd0 = (t & 3) * 32;   // K staging: 4 x b128
    const int vd   = t >> 1, vj0 = (t & 1) * 32;   // V staging: 4 x b128

    // per-lane row constants (no LDS)
    float ci_r[4], nfv_r[4];
    #pragma unroll
    for (int reg = 0; reg < 4; ++reg) {
        int rl = w * 16 + quad * 4 + reg;
        ci_r[reg]  = Cq[(size_t)bh * S_ + q0 + rl];
        nfv_r[reg] = NFi[(size_t)bh * S_ + q0 + rl];
    }
    // Q A-frags direct from f16 global
    half8 aq[4];
    {
        const _Float16* qrow = qh + ((size_t)bh * S_ + q0 + w * 16 + l15) * DH_;
        #pragma unroll
        for (int ks = 0; ks < 4; ++ks)
            aq[ks] = *(const half8*)(qrow + ks * 32 + quad * 8);
    }

    // ---- prefetch tile 0 (f16, 32 VGPRs) ----
    half8 kreg[4], vreg[4];
    float ajreg = 0.f;
    {
        const _Float16* kp = kh + ((size_t)bh * S_ + krow) * DH_ + kd0;
        const _Float16* vp = vtg + ((size_t)bh * DH_ + vd) * S_ + vj0;
        #pragma unroll
        for (int i = 0; i < 4; ++i) { kreg[i] = *(const half8*)(kp + i * 8);
                                      vreg[i] = *(const half8*)(vp + i * 8); }
    }
    if (t < 64) ajreg = Aj[(size_t)bh * S_ + t];

    // ---- stage tile 0 ----
    #pragma unroll
    for (int i = 0; i < 4; ++i) {
        *(half8*)(&Ks[krow * 136 + kd0 + i * 8]) = kreg[i];
        *(half8*)(&Vt[vd * 72 + vj0 + i * 8])    = vreg[i];
    }
    if (t < 64) aj[t] = ajreg;
    __syncthreads();

    floatx4 acc_h[8];
    #pragma unroll
    for (int i = 0; i < 8; ++i) acc_h[i] = (floatx4){0.f, 0.f, 0.f, 0.f};
    float lrun[4] = {0.f, 0.f, 0.f, 0.f};
    const float rscale = 0.08838834764831845f;   // 1/sqrt(128)

    for (int kt = 0; kt <= qi; ++kt) {
        // issue next-tile f16 loads; vmcnt waits land in the staging section
        if (kt < qi) {
            const int j0n = (kt + 1) * 64;
            const _Float16* kp = kh + ((size_t)bh * S_ + j0n + krow) * DH_ + kd0;
            const _Float16* vp = vtg + ((size_t)bh * DH_ + vd) * S_ + j0n + vj0;
            #pragma unroll
            for (int i = 0; i < 4; ++i) { kreg[i] = *(const half8*)(kp + i * 8);
                                          vreg[i] = *(const half8*)(vp + i * 8); }
            if (t < 64) ajreg = Aj[(size_t)bh * S_ + j0n + t];
        }

        // ---- compute run: QK -> P -> PV (Pb wave-private, no barrier) ----
        floatx4 sacc[4];
        #pragma unroll
        for (int nt = 0; nt < 4; ++nt) sacc[nt] = (floatx4){0.f, 0.f, 0.f, 0.f};
        #pragma unroll
        for (int ks = 0; ks < 4; ++ks) {
            #pragma unroll
            for (int nt = 0; nt < 4; ++nt) {
                half8 bk = *(const half8*)(&Ks[(nt * 16 + l15) * 136 + ks * 32 + quad * 8]);
                sacc[nt] = __builtin_amdgcn_mfma_f32_16x16x32_f16(aq[ks], bk, sacc[nt], 0, 0, 0);
            }
        }
        const bool diag = (kt == qi);
        #pragma unroll
        for (int nt = 0; nt < 4; ++nt) {
            int jl = nt * 16 + l15;
            float a_j = aj[jl];
            #pragma unroll
            for (int reg = 0; reg < 4; ++reg) {
                int rl = w * 16 + quad * 4 + reg;
                float p = 0.f;
                if (!diag || (jl <= rl))
                    p = sacc[nt][reg] * rscale * __expf(fminf(ci_r[reg] + a_j, 0.f));
                lrun[reg] += p;
                Pb[rl * 72 + jl] = (_Float16)p;
            }
        }
        #pragma unroll
        for (int ks2 = 0; ks2 < 2; ++ks2) {
            half8 ap = *(const half8*)(&Pb[(w * 16 + l15) * 72 + ks2 * 32 + quad * 8]);
            #pragma unroll
            for (int nt2 = 0; nt2 < 8; ++nt2) {
                half8 bv = *(const half8*)(&Vt[(nt2 * 16 + l15) * 72 + ks2 * 32 + quad * 8]);
                acc_h[nt2] = __builtin_amdgcn_mfma_f32_16x16x32_f16(ap, bv, acc_h[nt2], 0, 0, 0);
            }
        }

        __syncthreads();   // b1: all LDS reads of tile kt complete
        if (kt < qi) {
            #pragma unroll
            for (int i = 0; i < 4; ++i) {
                *(half8*)(&Ks[krow * 136 + kd0 + i * 8]) = kreg[i];
                *(half8*)(&Vt[vd * 72 + vj0 + i * 8])    = vreg[i];
            }
            if (t < 64) aj[t] = ajreg;
            __syncthreads();   // b2: tile kt+1 staged
        }
    }

    // epilogue: normalizer + per-head LayerNorm over DH
    #pragma unroll
    for (int reg = 0; reg < 4; ++reg) {
        float l = lrun[reg];
        #pragma unroll
        for (int off = 1; off < 16; off <<= 1) l += __shfl_xor(l, off);
        int rl = w * 16 + quad * 4 + reg;
        float nrm = fmaxf(fabsf(l), nfv_r[reg]) + EPS_;
        float inv = 1.f / nrm;
        float hv[8];
        float sum = 0.f, sq = 0.f;
        #pragma unroll
        for (int nt2 = 0; nt2 < 8; ++nt2) {
            float x = acc_h[nt2][reg] * inv;
            hv[nt2] = x; sum += x; sq += x * x;
        }
        #pragma unroll
        for (int off = 1; off < 16; off <<= 1) {
            sum += __shfl_xor(sum, off);
            sq  += __shfl_xor(sq, off);
        }
        float mean = sum * (1.f / 128.f);
        float var  = fmaxf(sq * (1.f / 128.f) - mean * mean, 0.f);
        float rstd = rsqrtf(var + EPS_);
        size_t orow = ((size_t)b * S_ + q0 + rl) * E_ + h * DH_;
        #pragma unroll
        for (int nt2 = 0; nt2 < 8; ++nt2) {
            int d = nt2 * 16 + l15;
            out[orow + d] = (hv[nt2] - mean) * rstd * lnsc[h * DH_ + d];
        }
    }
}

// ---------------------------------------------------------------------------
extern "C" void kernel_launch(void* const* d_in, const int* in_sizes, int n_in,
                              void* d_out, int out_size, void* d_ws, size_t ws_size,
                              hipStream_t stream)
{
    const float* q    = (const float*)d_in[0];
    const float* k    = (const float*)d_in[1];
    const float* v    = (const float*)d_in[2];
    const float* Wi   = (const float*)d_in[3];
    const float* bi   = (const float*)d_in[4];
    const float* Wf   = (const float*)d_in[5];
    const float* bfb  = (const float*)d_in[6];
    const float* lnsc = (const float*)d_in[7];
    float* out        = (float*)d_out;

    const int NS  = B_ * NH_ * S_;       // 32768
    float* pre_i = (float*)d_ws;         // [8][32][1024] partials
    float* pre_f = pre_i + 8 * NS;
    float* Aj    = pre_f + 8 * NS;
    float* Cq    = Aj + NS;
    float* NFa   = Cq + NS;
    _Float16* qh  = (_Float16*)(NFa + NS);          // [32][1024][128] f16
    _Float16* kh  = qh + (size_t)32 * S_ * DH_;
    _Float16* vtg = kh + (size_t)32 * S_ * DH_;     // [32][128][1024] f16

    prep_kernel<<<dim3(16, 32), 256, 0, stream>>>(q, k, v, qh, kh, vtg);
    gates_kernel<<<dim3(64, 8), 256, 0, stream>>>(q, k, v, Wi, Wf, pre_i, pre_f);
    scan_kernel<<<dim3(32), 64, 0, stream>>>(pre_i, pre_f, Aj, Cq, NFa, bi, bfb);
    attn_kernel<<<dim3(512), 256, 0, stream>>>(qh, kh, vtg, Aj, Cq, NFa, lnsc, out);
}

// Round 10
// 160.767 us; speedup vs baseline: 1.5407x; 1.2671x over previous
//
#include <hip/hip_runtime.h>
#include <hip/hip_bf16.h>

#define B_   2
#define S_   1024
#define E_   2048
#define NH_  16
#define DH_  128
#define EPS_ 1e-6f

using half8   = __attribute__((ext_vector_type(8))) _Float16;
using floatx4 = __attribute__((ext_vector_type(4))) float;

__device__ __forceinline__ half8 cvt8h(const float* __restrict__ p) {
    float4 a = *(const float4*)p;
    float4 b = *(const float4*)(p + 4);
    half8 r;
    r[0] = (_Float16)a.x; r[1] = (_Float16)a.y;
    r[2] = (_Float16)a.z; r[3] = (_Float16)a.w;
    r[4] = (_Float16)b.x; r[5] = (_Float16)b.y;
    r[6] = (_Float16)b.z; r[7] = (_Float16)b.w;
    return r;
}

// ---------------------------------------------------------------------------
// Kernel 0: pre-convert q,k -> f16 [bh][s][d]; v -> f16 TRANSPOSED [bh][d][s].
// ---------------------------------------------------------------------------
__global__ __launch_bounds__(256, 2) void prep_kernel(
    const float* __restrict__ q, const float* __restrict__ k,
    const float* __restrict__ v, _Float16* __restrict__ qh,
    _Float16* __restrict__ kh, _Float16* __restrict__ vtg)
{
    __shared__ __attribute__((aligned(16))) _Float16 vs[64 * 136];
    const int t  = threadIdx.x;
    const int st = blockIdx.x, bh = blockIdx.y;
    const int b  = bh >> 4, h = bh & 15;
    const int s0 = st * 64;
    const int r  = t >> 2, d0 = (t & 3) * 32;
    const size_t gin  = ((size_t)b * S_ + s0 + r) * E_ + h * DH_ + d0;
    const size_t gout = ((size_t)bh * S_ + s0 + r) * DH_ + d0;
    #pragma unroll
    for (int i = 0; i < 4; ++i)
        *(half8*)(qh + gout + i * 8) = cvt8h(q + gin + i * 8);
    #pragma unroll
    for (int i = 0; i < 4; ++i)
        *(half8*)(kh + gout + i * 8) = cvt8h(k + gin + i * 8);
    #pragma unroll
    for (int i = 0; i < 4; ++i)
        *(half8*)(&vs[r * 136 + d0 + i * 8]) = cvt8h(v + gin + i * 8);
    __syncthreads();
    const int d = t >> 1, j0 = (t & 1) * 32;
    _Float16 tmp[32];
    #pragma unroll
    for (int jj = 0; jj < 32; ++jj)
        tmp[jj] = vs[(j0 + jj) * 136 + d];      // 2-way banks (free)
    const size_t vout = ((size_t)bh * DH_ + d) * S_ + s0 + j0;
    #pragma unroll
    for (int i = 0; i < 4; ++i)
        *(half8*)(vtg + vout + i * 8) = *(half8*)(&tmp[i * 8]);
}

// ---------------------------------------------------------------------------
// Kernel 1: gate GEMM, K-split x8, no atomics (disjoint partial buffers).
// ---------------------------------------------------------------------------
__global__ __launch_bounds__(256, 4) void gates_kernel(
    const float* __restrict__ q, const float* __restrict__ k,
    const float* __restrict__ v, const float* __restrict__ Wi,
    const float* __restrict__ Wf, float* __restrict__ pre_i,
    float* __restrict__ pre_f)
{
    __shared__ __attribute__((aligned(16))) _Float16 xs[32 * 264];
    __shared__ __attribute__((aligned(16))) _Float16 wt[32 * 264];

    const int t    = threadIdx.x;
    const int w    = t >> 6, lane = t & 63, quad = lane >> 4, l15 = lane & 15;
    const int mw   = w & 1, nw = w >> 1;
    const int m0   = blockIdx.x * 32;
    const int by   = blockIdx.y;
    const int kbase = by * 768;

    floatx4 acc = {0.f, 0.f, 0.f, 0.f};

    for (int c = 0; c < 3; ++c) {
        __syncthreads();
        const int e0   = kbase + c * 256;
        const int tsel = e0 >> 11;            // 0:q 1:k 2:v
        const int el0  = e0 & 2047;
        const float* xb = (tsel == 0) ? q : (tsel == 1) ? k : v;
        #pragma unroll
        for (int i = 0; i < 4; ++i) {
            int g = t + i * 256;
            int row = g >> 5, grp = g & 31;
            half8 s8 = cvt8h(xb + (size_t)(m0 + row) * E_ + el0 + grp * 8);
            *(half8*)(&xs[row * 264 + grp * 8]) = s8;
        }
        {
            const int kk = t;
            const float* wiRow = Wi + (size_t)(e0 + kk) * NH_;
            const float* wfRow = Wf + (size_t)(e0 + kk) * NH_;
            float wif[16], wff[16];
            #pragma unroll
            for (int i4 = 0; i4 < 4; ++i4) {
                float4 a = *(const float4*)(wiRow + i4 * 4);
                wif[i4*4+0]=a.x; wif[i4*4+1]=a.y; wif[i4*4+2]=a.z; wif[i4*4+3]=a.w;
                float4 b = *(const float4*)(wfRow + i4 * 4);
                wff[i4*4+0]=b.x; wff[i4*4+1]=b.y; wff[i4*4+2]=b.z; wff[i4*4+3]=b.w;
            }
            #pragma unroll
            for (int hh = 0; hh < 16; ++hh) wt[hh * 264 + kk]        = (_Float16)wif[hh];
            #pragma unroll
            for (int hh = 0; hh < 16; ++hh) wt[(16 + hh) * 264 + kk] = (_Float16)wff[hh];
        }
        __syncthreads();
        #pragma unroll
        for (int ks = 0; ks < 8; ++ks) {
            half8 af = *(const half8*)(&xs[(mw * 16 + l15) * 264 + ks * 32 + quad * 8]);
            half8 bw = *(const half8*)(&wt[(nw * 16 + l15) * 264 + ks * 32 + quad * 8]);
            acc = __builtin_amdgcn_mfma_f32_16x16x32_f16(af, bw, acc, 0, 0, 0);
        }
    }
    #pragma unroll
    for (int reg = 0; reg < 4; ++reg) {
        int m   = m0 + mw * 16 + quad * 4 + reg;
        int b   = m >> 10, s = m & 1023;
        int col = nw * 16 + l15;
        float vacc = acc[reg];
        if (col < 16)
            pre_i[((size_t)(by * 32 + b * NH_ + col)) * S_ + s] = vacc;
        else
            pre_f[((size_t)(by * 32 + b * NH_ + col - 16)) * S_ + s] = vacc;
    }
}

// ---------------------------------------------------------------------------
// Kernel 2: two-level block-parallel scan. 1024 threads per (b,h); each
// thread owns one s. Wave-level shfl scans + LDS carry combine.
// ---------------------------------------------------------------------------
__global__ __launch_bounds__(1024, 1) void scan_kernel(
    const float* __restrict__ pre_i, const float* __restrict__ pre_f,
    float* __restrict__ Aj, float* __restrict__ Cq,
    float* __restrict__ NFo, const float* __restrict__ bi,
    const float* __restrict__ bfb)
{
    __shared__ float wsumF[16], wmaxA[16];
    const int bh   = blockIdx.x;
    const int h    = bh & 15;
    const int t    = threadIdx.x;        // = s
    const int lane = t & 63, wv = t >> 6;

    float igv = bi[h], x = bfb[h];
    #pragma unroll
    for (int y = 0; y < 8; ++y) {        // 16 parallel loads
        igv += pre_i[((size_t)(y * 32 + bh)) * S_ + t];
        x   += pre_f[((size_t)(y * 32 + bh)) * S_ + t];
    }
    float lfv = (x >= 0.f) ? -log1pf(__expf(-x)) : (x - log1pf(__expf(x)));

    // level 1: wave inclusive sum-scan of lf
    float sc = lfv;
    #pragma unroll
    for (int off = 1; off < 64; off <<= 1) {
        float o = __shfl_up(sc, off);
        if (lane >= off) sc += o;
    }
    if (lane == 63) wsumF[wv] = sc;
    __syncthreads();
    // level 2: prefix offset across waves (wave-uniform loop, broadcast reads)
    float Foff = 0.f;
    for (int i = 0; i < wv; ++i) Foff += wsumF[i];
    float F = Foff + sc;
    float a = igv - F;

    // level 1: wave inclusive max-scan of a
    float ms = a;
    #pragma unroll
    for (int off = 1; off < 64; off <<= 1) {
        float o = __shfl_up(ms, off);
        if (lane >= off) ms = fmaxf(ms, o);
    }
    if (lane == 63) wmaxA[wv] = ms;
    __syncthreads();
    float Moff = -3.0e38f;
    for (int i = 0; i < wv; ++i) Moff = fmaxf(Moff, wmaxA[i]);
    float M = fmaxf(Moff, ms);

    size_t o = (size_t)bh * S_ + t;
    Aj[o]  = a;
    Cq[o]  = -M;
    NFo[o] = expf(fminf(-(F + M), 80.f));
}

// ---------------------------------------------------------------------------
// Kernel 3: fused causal attention on pre-converted f16 inputs.
// ---------------------------------------------------------------------------
__global__ __launch_bounds__(256, 2) void attn_kernel(
    const _Float16* __restrict__ qh, const _Float16* __restrict__ kh,
    const _Float16* __restrict__ vtg, const float* __restrict__ Aj,
    const float* __restrict__ Cq, const float* __restrict__ NFi,
    const float* __restrict__ lnsc, float* __restrict__ out)
{
    __shared__ __attribute__((aligned(16))) _Float16 Ks[64 * 136];
    __shared__ __attribute__((aligned(16))) _Float16 Vt[128 * 72];
    __shared__ __attribute__((aligned(16))) _Float16 Pb[64 * 72];
    __shared__ float aj[64];

    const int t    = threadIdx.x;
    const int w    = t >> 6, lane = t & 63, quad = lane >> 4, l15 = lane & 15;
    const int L    = blockIdx.x;
    int qi, bh;
    if (L < 256) { qi = L >> 5;                bh = L & 31; }
    else         { qi = 15 - ((L - 256) >> 5); bh = (L - 256) & 31; }
    const int b    = bh >> 4, h = bh & 15;
    const int q0   = qi * 64;
    const int krow = t >> 2, kd0 = (t & 3) * 32;   // K staging: 4 x b128
    const int vd   = t >> 1, vj0 = (t & 1) * 32;   // V staging: 4 x b128

    float ci_r[4], nfv_r[4];
    #pragma unroll
    for (int reg = 0; reg < 4; ++reg) {
        int rl = w * 16 + quad * 4 + reg;
        ci_r[reg]  = Cq[(size_t)bh * S_ + q0 + rl];
        nfv_r[reg] = NFi[(size_t)bh * S_ + q0 + rl];
    }
    half8 aq[4];
    {
        const _Float16* qrow = qh + ((size_t)bh * S_ + q0 + w * 16 + l15) * DH_;
        #pragma unroll
        for (int ks = 0; ks < 4; ++ks)
            aq[ks] = *(const half8*)(qrow + ks * 32 + quad * 8);
    }

    // ---- prefetch tile 0 (f16, 32 VGPRs) ----
    half8 kreg[4], vreg[4];
    float ajreg = 0.f;
    {
        const _Float16* kp = kh + ((size_t)bh * S_ + krow) * DH_ + kd0;
        const _Float16* vp = vtg + ((size_t)bh * DH_ + vd) * S_ + vj0;
        #pragma unroll
        for (int i = 0; i < 4; ++i) { kreg[i] = *(const half8*)(kp + i * 8);
                                      vreg[i] = *(const half8*)(vp + i * 8); }
    }
    if (t < 64) ajreg = Aj[(size_t)bh * S_ + t];

    #pragma unroll
    for (int i = 0; i < 4; ++i) {
        *(half8*)(&Ks[krow * 136 + kd0 + i * 8]) = kreg[i];
        *(half8*)(&Vt[vd * 72 + vj0 + i * 8])    = vreg[i];
    }
    if (t < 64) aj[t] = ajreg;
    __syncthreads();

    floatx4 acc_h[8];
    #pragma unroll
    for (int i = 0; i < 8; ++i) acc_h[i] = (floatx4){0.f, 0.f, 0.f, 0.f};
    float lrun[4] = {0.f, 0.f, 0.f, 0.f};
    const float rscale = 0.08838834764831845f;   // 1/sqrt(128)

    for (int kt = 0; kt <= qi; ++kt) {
        if (kt < qi) {
            const int j0n = (kt + 1) * 64;
            const _Float16* kp = kh + ((size_t)bh * S_ + j0n + krow) * DH_ + kd0;
            const _Float16* vp = vtg + ((size_t)bh * DH_ + vd) * S_ + j0n + vj0;
            #pragma unroll
            for (int i = 0; i < 4; ++i) { kreg[i] = *(const half8*)(kp + i * 8);
                                          vreg[i] = *(const half8*)(vp + i * 8); }
            if (t < 64) ajreg = Aj[(size_t)bh * S_ + j0n + t];
        }

        // ---- compute run: QK -> P -> PV (Pb wave-private, no barrier) ----
        floatx4 sacc[4];
        #pragma unroll
        for (int nt = 0; nt < 4; ++nt) sacc[nt] = (floatx4){0.f, 0.f, 0.f, 0.f};
        #pragma unroll
        for (int ks = 0; ks < 4; ++ks) {
            #pragma unroll
            for (int nt = 0; nt < 4; ++nt) {
                half8 bk = *(const half8*)(&Ks[(nt * 16 + l15) * 136 + ks * 32 + quad * 8]);
                sacc[nt] = __builtin_amdgcn_mfma_f32_16x16x32_f16(aq[ks], bk, sacc[nt], 0, 0, 0);
            }
        }
        const bool diag = (kt == qi);
        #pragma unroll
        for (int nt = 0; nt < 4; ++nt) {
            int jl = nt * 16 + l15;
            float a_j = aj[jl];
            #pragma unroll
            for (int reg = 0; reg < 4; ++reg) {
                int rl = w * 16 + quad * 4 + reg;
                float p = 0.f;
                if (!diag || (jl <= rl))
                    p = sacc[nt][reg] * rscale * __expf(fminf(ci_r[reg] + a_j, 0.f));
                lrun[reg] += p;
                Pb[rl * 72 + jl] = (_Float16)p;
            }
        }
        #pragma unroll
        for (int ks2 = 0; ks2 < 2; ++ks2) {
            half8 ap = *(const half8*)(&Pb[(w * 16 + l15) * 72 + ks2 * 32 + quad * 8]);
            #pragma unroll
            for (int nt2 = 0; nt2 < 8; ++nt2) {
                half8 bv = *(const half8*)(&Vt[(nt2 * 16 + l15) * 72 + ks2 * 32 + quad * 8]);
                acc_h[nt2] = __builtin_amdgcn_mfma_f32_16x16x32_f16(ap, bv, acc_h[nt2], 0, 0, 0);
            }
        }

        __syncthreads();   // b1: all LDS reads of tile kt complete
        if (kt < qi) {
            #pragma unroll
            for (int i = 0; i < 4; ++i) {
                *(half8*)(&Ks[krow * 136 + kd0 + i * 8]) = kreg[i];
                *(half8*)(&Vt[vd * 72 + vj0 + i * 8])    = vreg[i];
            }
            if (t < 64) aj[t] = ajreg;
            __syncthreads();   // b2: tile kt+1 staged
        }
    }

    // epilogue: normalizer + per-head LayerNorm over DH
    #pragma unroll
    for (int reg = 0; reg < 4; ++reg) {
        float l = lrun[reg];
        #pragma unroll
        for (int off = 1; off < 16; off <<= 1) l += __shfl_xor(l, off);
        int rl = w * 16 + quad * 4 + reg;
        float nrm = fmaxf(fabsf(l), nfv_r[reg]) + EPS_;
        float inv = 1.f / nrm;
        float hv[8];
        float sum = 0.f, sq = 0.f;
        #pragma unroll
        for (int nt2 = 0; nt2 < 8; ++nt2) {
            float x = acc_h[nt2][reg] * inv;
            hv[nt2] = x; sum += x; sq += x * x;
        }
        #pragma unroll
        for (int off = 1; off < 16; off <<= 1) {
            sum += __shfl_xor(sum, off);
            sq  += __shfl_xor(sq, off);
        }
        float mean = sum * (1.f / 128.f);
        float var  = fmaxf(sq * (1.f / 128.f) - mean * mean, 0.f);
        float rstd = rsqrtf(var + EPS_);
        size_t orow = ((size_t)b * S_ + q0 + rl) * E_ + h * DH_;
        #pragma unroll
        for (int nt2 = 0; nt2 < 8; ++nt2) {
            int d = nt2 * 16 + l15;
            out[orow + d] = (hv[nt2] - mean) * rstd * lnsc[h * DH_ + d];
        }
    }
}

// ---------------------------------------------------------------------------
extern "C" void kernel_launch(void* const* d_in, const int* in_sizes, int n_in,
                              void* d_out, int out_size, void* d_ws, size_t ws_size,
                              hipStream_t stream)
{
    const float* q    = (const float*)d_in[0];
    const float* k    = (const float*)d_in[1];
    const float* v    = (const float*)d_in[2];
    const float* Wi   = (const float*)d_in[3];
    const float* bi   = (const float*)d_in[4];
    const float* Wf   = (const float*)d_in[5];
    const float* bfb  = (const float*)d_in[6];
    const float* lnsc = (const float*)d_in[7];
    float* out        = (float*)d_out;

    const int NS  = B_ * NH_ * S_;       // 32768
    float* pre_i = (float*)d_ws;         // [8][32][1024] partials
    float* pre_f = pre_i + 8 * NS;
    float* Aj    = pre_f + 8 * NS;
    float* Cq    = Aj + NS;
    float* NFa   = Cq + NS;
    _Float16* qh  = (_Float16*)(NFa + NS);          // [32][1024][128] f16
    _Float16* kh  = qh + (size_t)32 * S_ * DH_;
    _Float16* vtg = kh + (size_t)32 * S_ * DH_;     // [32][128][1024] f16

    prep_kernel<<<dim3(16, 32), 256, 0, stream>>>(q, k, v, qh, kh, vtg);
    gates_kernel<<<dim3(64, 8), 256, 0, stream>>>(q, k, v, Wi, Wf, pre_i, pre_f);
    scan_kernel<<<dim3(32), 1024, 0, stream>>>(pre_i, pre_f, Aj, Cq, NFa, bi, bfb);
    attn_kernel<<<dim3(512), 256, 0, stream>>>(qh, kh, vtg, Aj, Cq, NFa, lnsc, out);
}